// Round 4
// baseline (236.684 us; speedup 1.0000x reference)
//
#include <hip/hip_runtime.h>
#include <math.h>

// Capsule routing, no u_hat materialization.
// Round 4: k_route phase-1 stall fix — Tst staged once (swizzled, no per-kc t
// loads), Us natural-layout k-vectorized (no transpose scatter), double-buffered
// with register prefetch -> ONE barrier per kc (16 vs 32). 256 thr, acc[4][4].
// Workspace: t(2MB) + sp(16MB) + sp0(0.5MB) = 18.5 MB.

#define B   64
#define IN  1024
#define ID  256
#define NC  32
#define DC  64

// ---------------------------------------------------------------------------
// sp0[c][b][d] = sum over i-chunk c of u[b][i][d]   (8 chunks of 128 i)
__global__ __launch_bounds__(256) void k_sumu(const float* __restrict__ u,
                                              float* __restrict__ sp0) {
    const int c = blockIdx.x, b = blockIdx.y;
    const int d = threadIdx.x;
    const float* up = u + ((size_t)b * IN + (size_t)c * (IN / 8)) * ID + d;
    float acc = 0.f;
#pragma unroll 8
    for (int i = 0; i < IN / 8; ++i) acc += up[(size_t)i * ID];
    sp0[(c * B + b) * ID + d] = acc;
}

// ---------------------------------------------------------------------------
// Per (b,n): s = (reduced partials); o = W_n s ; then
//   mode 0: s from sp0 (uniform c=1/32), normalize o, t = W_n^T o_norm
//   mode 1: s from sp,                  normalize o, t = W_n^T o_norm
//   mode 2: s from sp, squash(o) -> out
__global__ __launch_bounds__(256) void k_ot(const float* __restrict__ W,
                                            const float* __restrict__ src,
                                            float* __restrict__ tout,
                                            const int mode) {
    const int bn = blockIdx.x;
    const int b = bn / NC, n = bn % NC;
    __shared__ float s_lds[ID];
    __shared__ float o_lds[DC];
    __shared__ float on_lds[DC];
    const int tid = threadIdx.x;

    float sv = 0.f;
    if (mode == 0) {
#pragma unroll
        for (int c = 0; c < 8; ++c) sv += src[(c * B + b) * ID + tid];
        sv *= (1.0f / NC);
    } else {
#pragma unroll
        for (int c = 0; c < 8; ++c) sv += src[((size_t)(c * B + b) * NC + n) * ID + tid];
    }
    s_lds[tid] = sv;
    __syncthreads();

    const int wave = tid >> 6, lane = tid & 63;
    const float* Wn = W + (size_t)n * DC * ID;
#pragma unroll 4
    for (int r = 0; r < 16; ++r) {
        const int d = wave * 16 + r;
        const float* wrow = Wn + (size_t)d * ID;
        float p = wrow[lane]        * s_lds[lane]
                + wrow[lane + 64]   * s_lds[lane + 64]
                + wrow[lane + 128]  * s_lds[lane + 128]
                + wrow[lane + 192]  * s_lds[lane + 192];
#pragma unroll
        for (int off = 32; off > 0; off >>= 1) p += __shfl_down(p, off);
        if (lane == 0) o_lds[d] = p;
    }
    __syncthreads();

    if (mode == 2) {
        if (tid < DC) {
            float v = o_lds[tid];
            float sq = v * v;
#pragma unroll
            for (int off = 32; off > 0; off >>= 1) sq += __shfl_down(sq, off);
            sq = __shfl(sq, 0) + 1e-7f;
            const float sc = sqrtf(sq) / (0.5f + sq);
            tout[(size_t)(b * NC + n) * DC + tid] = v * sc;
        }
        return;
    }

    if (tid < DC) {
        float v = o_lds[tid];
        float sq = v * v;
#pragma unroll
        for (int off = 32; off > 0; off >>= 1) sq += __shfl_down(sq, off);
        sq = __shfl(sq, 0);
        const float inv = 1.0f / fmaxf(sqrtf(sq), 1e-12f);
        on_lds[tid] = v * inv;
    }
    __syncthreads();

    float acc = 0.f;
    const float* wc = Wn + tid;
#pragma unroll 8
    for (int d = 0; d < DC; ++d) acc += wc[(size_t)d * ID] * on_lds[d];
    tout[((size_t)b * NC + n) * ID + tid] = acc;
}

// ---------------------------------------------------------------------------
// Fused routing step. Block: (i-tile of 128, b), 256 threads, LDS 70.9 KB.
//   phase 1: logits[i][n] = u[i,:].t[n,:]  — Tst LDS-resident (swizzled),
//            Us double-buffered 16-k chunks, ONE barrier per chunk, reg prefetch.
//   phase 2: softmax over n (in LDS)
//   phase 3: sp[it][b][n][d] = sum_i c[i][n] u[i][d]  (u re-read, L2-hot)
#define RTILE 128
__global__ __launch_bounds__(256) void k_route(const float* __restrict__ u,
                                               const float* __restrict__ t,
                                               float* __restrict__ sp) {
    const int it = blockIdx.x, b = blockIdx.y;
    const int iBase = it * RTILE;
    __shared__ __align__(16) float Tst[NC][ID];       // t[b] swizzled rows (32 KB)
    __shared__ __align__(16) float Us[2][RTILE][20];  // u chunk, dbuf     (20.5 KB)
    __shared__ __align__(16) float cl[RTILE][36];     // coeffs            (18.4 KB)
    const int tid = threadIdx.x;

    const float* ub = u + ((size_t)b * IN + iBase) * ID;
    const float* tb = t + (size_t)b * NC * ID;

    // ---- stage Tst once: 32 n x 64 f4-cols, col-swizzled by ((n>>2)&7)<<2 ----
#pragma unroll
    for (int rep = 0; rep < 8; ++rep) {
        const int idx = tid + rep * 256;          // 2048 f4 total
        const int n = idx >> 6, c4 = idx & 63;
        const float4 v = *(const float4*)(tb + (size_t)n * ID + c4 * 4);
        const int c_sw = (c4 * 4) ^ (((n >> 2) & 7) << 2);
        *(float4*)&Tst[n][c_sw] = v;
    }

    // ---- phase 1: logits, kc chunks of 16 k, double-buffered Us ----
    const int q = tid >> 3;   // i-group: i0 = q*4   (32 groups)
    const int r = tid & 7;    // n-group: n0 = r*4   (8 groups)
    const int i0 = q * 4, n0 = r * 4;
    // staging map: 512 f4 per chunk, 2 per thread
    const int si0 = tid >> 2,        sk0 = tid & 3;          // rep 0
    const int si1 = (tid + 256) >> 2, sk1 = (tid + 256) & 3; // rep 1
    const int sc0 = 4 * (sk0 ^ ((si0 >> 2) & 3));
    const int sc1 = 4 * (sk1 ^ ((si1 >> 2) & 3));
    const int qs = q & 3;     // read-side k4 swizzle key (== (i>>2)&3 for i0..i0+3)

    float acc[4][4] = {{0.f}};
    float4 pre0 = *(const float4*)(ub + (size_t)si0 * ID + sk0 * 4);
    float4 pre1 = *(const float4*)(ub + (size_t)si1 * ID + sk1 * 4);

    for (int kc = 0; kc < ID / 16; ++kc) {
        const int buf = kc & 1;
        *(float4*)&Us[buf][si0][sc0] = pre0;
        *(float4*)&Us[buf][si1][sc1] = pre1;
        __syncthreads();
        if (kc < ID / 16 - 1) {   // issue next chunk early (T14): latency hides under compute
            pre0 = *(const float4*)(ub + (size_t)si0 * ID + (kc + 1) * 16 + sk0 * 4);
            pre1 = *(const float4*)(ub + (size_t)si1 * ID + (kc + 1) * 16 + sk1 * 4);
        }
#pragma unroll
        for (int k4 = 0; k4 < 4; ++k4) {
            float4 a[4], bv[4];
            const int ac = 4 * (k4 ^ qs);
#pragma unroll
            for (int ii = 0; ii < 4; ++ii) a[ii] = *(const float4*)&Us[buf][i0 + ii][ac];
            const int bc = (kc * 16 + k4 * 4) ^ (r << 2);
#pragma unroll
            for (int jj = 0; jj < 4; ++jj) bv[jj] = *(const float4*)&Tst[n0 + jj][bc];
#pragma unroll
            for (int ii = 0; ii < 4; ++ii)
#pragma unroll
                for (int jj = 0; jj < 4; ++jj)
                    acc[ii][jj] += a[ii].x * bv[jj].x + a[ii].y * bv[jj].y
                                 + a[ii].z * bv[jj].z + a[ii].w * bv[jj].w;
        }
        __syncthreads();   // all reads of Us[buf] done before it's overwritten (kc+2)
    }

    // logits -> cl
#pragma unroll
    for (int ii = 0; ii < 4; ++ii)
        *(float4*)&cl[i0 + ii][n0] =
            make_float4(acc[ii][0], acc[ii][1], acc[ii][2], acc[ii][3]);
    __syncthreads();

    // ---- phase 2: softmax over 32 n; 2 threads per i (16 n each) ----
    {
        const int i = tid >> 1, half = tid & 1;
        float v[16];
#pragma unroll
        for (int j = 0; j < 16; ++j) v[j] = cl[i][half * 16 + j];
        float mx = v[0];
#pragma unroll
        for (int j = 1; j < 16; ++j) mx = fmaxf(mx, v[j]);
        mx = fmaxf(mx, __shfl_xor(mx, 1));
        float sum = 0.f;
#pragma unroll
        for (int j = 0; j < 16; ++j) { v[j] = __expf(v[j] - mx); sum += v[j]; }
        sum += __shfl_xor(sum, 1);
        const float inv = 1.0f / sum;
#pragma unroll
        for (int j = 0; j < 16; ++j) cl[i][half * 16 + j] = v[j] * inv;
    }
    __syncthreads();

    // ---- phase 3: weighted aggregation (u tile re-read, L2-hot) ----
    const int d4 = tid & 63;       // float4 index into ID
    const int ng = tid >> 6;       // n base = ng*8 (wave-uniform -> LDS broadcast)
    float a2[8][4] = {{0.f}};
    const float* ur = ub + d4 * 4;
#pragma unroll 4
    for (int i = 0; i < RTILE; ++i) {
        const float4 uv = *(const float4*)(ur + (size_t)i * ID);
        const float4 c0 = *(const float4*)&cl[i][ng * 8];
        const float4 c1 = *(const float4*)&cl[i][ng * 8 + 4];
        const float cv[8] = {c0.x, c0.y, c0.z, c0.w, c1.x, c1.y, c1.z, c1.w};
        const float uvv[4] = {uv.x, uv.y, uv.z, uv.w};
#pragma unroll
        for (int j = 0; j < 8; ++j)
#pragma unroll
            for (int x = 0; x < 4; ++x) a2[j][x] += cv[j] * uvv[x];
    }

    float* spb = sp + (size_t)(it * B + b) * NC * ID;
#pragma unroll
    for (int j = 0; j < 8; ++j) {
        const int n = ng * 8 + j;
        *(float4*)&spb[(size_t)n * ID + d4 * 4] =
            make_float4(a2[j][0], a2[j][1], a2[j][2], a2[j][3]);
    }
}

// ---------------------------------------------------------------------------
extern "C" void kernel_launch(void* const* d_in, const int* in_sizes, int n_in,
                              void* d_out, int out_size, void* d_ws, size_t ws_size,
                              hipStream_t stream) {
    const float* u = (const float*)d_in[0];   // [B][IN][ID]
    const float* W = (const float*)d_in[1];   // [NC*DC][ID]
    float* out = (float*)d_out;               // [B][NC][DC]

    float* ws  = (float*)d_ws;
    float* t   = ws;                                   // B*NC*ID      = 0.5M floats
    float* sp  = t + (size_t)B * NC * ID;              // 8*B*NC*ID    = 4M floats
    float* sp0 = sp + (size_t)8 * B * NC * ID;         // 8*B*ID       = 128K floats

    // routing iteration 0 (c uniform = 1/32)
    k_sumu <<<dim3(8, B), dim3(256), 0, stream>>>(u, sp0);
    k_ot   <<<dim3(B * NC), dim3(256), 0, stream>>>(W, sp0, t, 0);
    // iteration 1 (logits + softmax + aggregate fused)
    k_route<<<dim3(IN / RTILE, B), dim3(256), 0, stream>>>(u, t, sp);
    k_ot   <<<dim3(B * NC), dim3(256), 0, stream>>>(W, sp, t, 1);
    // iteration 2
    k_route<<<dim3(IN / RTILE, B), dim3(256), 0, stream>>>(u, t, sp);
    k_ot   <<<dim3(B * NC), dim3(256), 0, stream>>>(W, sp, out, 2);
}